// Round 3
// baseline (6315.944 us; speedup 1.0000x reference)
//
#include <hip/hip_runtime.h>
#include <cstdint>

#define B_    8
#define T_    16384
#define NA_   512
#define A_    512
#define NIT_  32
#define SEG_  1024
#define NSEG_ 16
#define EPSV  1e-8f
#define DEXSZ 2064

// d_out scratch layout (float offsets); all dead by the time k_final writes out
#define DO_SEG   0          // u64 seg[G*NA_*NSEG_]   (<=131072 floats)
#define DO_RMA   131072     // u64 rowMaxA[G*NA_]     (<=8192 floats)
#define DO_RMB   139264     // u64 rowMaxB[G*NA_]
#define DO_SEL   147456     // selA[256] selT[256] selV[256]  (768 floats)
#define DO_INV   148224     // inv[512]
#define DO_SCN   (768 + 512)  // floats copied to ws before k_final

__device__ __forceinline__ unsigned int encf(float f) {
    unsigned int u = __float_as_uint(f);
    return (u & 0x80000000u) ? ~u : (u | 0x80000000u);
}
__device__ __forceinline__ float decf(unsigned int e) {
    unsigned int u = (e & 0x80000000u) ? (e & 0x7fffffffu) : ~e;
    return __uint_as_float(u);
}
__device__ __forceinline__ unsigned long long umax64(unsigned long long a, unsigned long long b) {
    return a > b ? a : b;
}
__device__ __forceinline__ unsigned long long shfl_xor_u64(unsigned long long v, int mask) {
    unsigned int lo = (unsigned int)v, hi = (unsigned int)(v >> 32);
    lo = __shfl_xor(lo, mask, 64);
    hi = __shfl_xor(hi, mask, 64);
    return (((unsigned long long)hi) << 32) | lo;
}

// ---------------- per-atom inverse norms: inv[a] = 1/(||d_a|| + eps) ----------------
__global__ __launch_bounds__(64) void k_inv(const float* __restrict__ d, float* __restrict__ inv) {
    const int a = blockIdx.x, lane = threadIdx.x;
    const float* row = d + a * A_;
    float s = 0.f;
    for (int i = lane; i < A_; i += 64) { float v = row[i]; s = fmaf(v, v, s); }
    #pragma unroll
    for (int o = 32; o > 0; o >>= 1) s += __shfl_down(s, o, 64);
    if (lane == 0) inv[a] = 1.0f / (sqrtf(s) + EPSV);
}

// ---------------- zero the u64 seg table ----------------
__global__ void k_init(unsigned long long* __restrict__ seg, int n) {
    int i = blockIdx.x * 256 + threadIdx.x;
    if (i < n) seg[i] = 0ull;
}

// ---------------- initial full correlation fm[gb,a,t] (normalized) + seg candidates ----------------
__global__ __launch_bounds__(256) void k_conv(const float* __restrict__ x,
                                              const float* __restrict__ d,
                                              const float* __restrict__ inv,
                                              float* __restrict__ fm,
                                              unsigned long long* __restrict__ seg0,
                                              int bg0) {
    __shared__ float As[32][68];
    __shared__ float Xs[160];
    const int tid = threadIdx.x;
    const int t0 = blockIdx.x * 128;
    const int a0 = blockIdx.y * 64;
    const int gb = blockIdx.z;
    const int tt = tid & 31;
    const int mb = tid >> 5;
    const float* xb = x + (bg0 + gb) * T_;

    float acc[8][4];
    #pragma unroll
    for (int p = 0; p < 8; ++p)
        #pragma unroll
        for (int q = 0; q < 4; ++q) acc[p][q] = 0.f;

    for (int k0 = 0; k0 < A_; k0 += 32) {
        #pragma unroll
        for (int mm = 0; mm < 8; ++mm) {
            int m = mb * 8 + mm;
            As[tt][m] = d[(a0 + m) * A_ + k0 + tt];
        }
        if (tid < 160) {
            int g = t0 + k0 + tid;
            Xs[tid] = (g < T_) ? xb[g] : 0.f;
        }
        __syncthreads();
        #pragma unroll
        for (int k = 0; k < 32; ++k) {           // full unroll: static LDS offsets
            float4 aA = *(const float4*)&As[k][mb * 8];
            float4 aB = *(const float4*)&As[k][mb * 8 + 4];
            float am[8] = {aA.x, aA.y, aA.z, aA.w, aB.x, aB.y, aB.z, aB.w};
            float xm[4] = {Xs[k + tt], Xs[k + tt + 32], Xs[k + tt + 64], Xs[k + tt + 96]};
            #pragma unroll
            for (int p = 0; p < 8; ++p)
                #pragma unroll
                for (int q = 0; q < 4; ++q)
                    acc[p][q] = fmaf(am[p], xm[q], acc[p][q]);
        }
        __syncthreads();
    }

    const int sidx = t0 >> 10;
    #pragma unroll
    for (int p = 0; p < 8; ++p) {
        int m = mb * 8 + p;
        float iv = inv[a0 + m];
        size_t row = (size_t)(gb * NA_ + a0 + m) * T_;
        unsigned long long cand = 0ull;
        #pragma unroll
        for (int q = 0; q < 4; ++q) {
            int t = t0 + tt + 32 * q;
            float val = acc[p][q] * iv;
            fm[row + t] = val;
            unsigned int flat = (unsigned int)((a0 + m) * T_ + t);
            unsigned long long c = (((unsigned long long)encf(val)) << 32) | (unsigned int)~flat;
            cand = umax64(cand, c);
        }
        #pragma unroll
        for (int o = 1; o < 32; o <<= 1) cand = umax64(cand, shfl_xor_u64(cand, o));
        if (tt == 0)
            atomicMax(&seg0[(gb * NA_ + a0 + m) * NSEG_ + sidx], cand);
    }
}

// ---------------- seg row -> rowMax table ----------------
__global__ void k_rowmax(const unsigned long long* __restrict__ seg,
                         unsigned long long* __restrict__ rm, int nrows) {
    int r = blockIdx.x * 256 + threadIdx.x;
    if (r < nrows) {
        const unsigned long long* p = seg + r * NSEG_;
        unsigned long long m = 0ull;
        #pragma unroll
        for (int i = 0; i < NSEG_; ++i) m = umax64(m, p[i]);
        rm[r] = m;
    }
}

// ---------------- fused per-iteration: select + incremental update + table maintenance ----------------
__global__ __launch_bounds__(128) void k_iter(float* __restrict__ fm,
                                              const float* __restrict__ d,
                                              const float* __restrict__ inv,
                                              unsigned long long* __restrict__ seg,
                                              const unsigned long long* __restrict__ rmOld,
                                              unsigned long long* __restrict__ rmNew,
                                              int* __restrict__ selA,
                                              int* __restrict__ selT,
                                              float* __restrict__ selV,
                                              int it, int bg0) {
    __shared__ unsigned long long redU[128];
    __shared__ float dEx[DEXSZ];   // zero-padded raw d row: absorbs all bounds checks
    __shared__ float w[528];
    const int aB = blockIdx.x;
    const int gb = blockIdx.y;
    const int tid = threadIdx.x;

    // ---- phase A: selection from 512-entry rowMax (all blocks identical) ----
    const ulonglong2* rb = (const ulonglong2*)(rmOld + gb * NA_);
    ulonglong2 e0 = rb[tid * 2];
    ulonglong2 e1 = rb[tid * 2 + 1];
    redU[tid] = umax64(umax64(e0.x, e0.y), umax64(e1.x, e1.y));
    __syncthreads();
    for (int s = 64; s > 0; s >>= 1) {
        if (tid < s) redU[tid] = umax64(redU[tid], redU[tid + s]);
        __syncthreads();
    }
    const unsigned long long win = redU[0];
    __syncthreads();
    const unsigned int enc = (unsigned int)(win >> 32);
    const unsigned int flat = ~(unsigned int)win;
    const int asel = (int)(flat >> 14);
    const int tsel = (int)(flat & (T_ - 1));
    const float v = decf(enc);
    if (tid == 0 && aB == 0) {
        int b = bg0 + gb;
        selA[it * B_ + b] = asel;
        selT[it * B_ + b] = tsel;
        selV[it * B_ + b] = v;
    }

    const int L = min(A_, (T_ - 1) - tsel);
    const size_t rowoff = (size_t)(gb * NA_ + aB) * T_;
    unsigned long long* segrow = seg + (gb * NA_ + aB) * NSEG_;
    int s0 = 1, s1 = 0;

    if (L > 0) {
        const int tbeg = max(0, tsel - (A_ - 1));
        const int tend = tsel + L;
        s0 = tbeg >> 10;
        s1 = (tend - 1) >> 10;
        const int C = 1024 + ((4 - ((tsel - tbeg) & 3)) & 3);  // keeps per-thread base 16B aligned
        const float vw = v * inv[asel];
        const float inv_aB = inv[aB];

        for (int i = tid; i < DEXSZ; i += 128) dEx[i] = 0.f;
        __syncthreads();
        for (int i = tid; i < A_; i += 128) dEx[C + i] = d[aB * A_ + i];
        for (int i = tid; i < 528; i += 128) w[i] = (i < L) ? vw * d[asel * A_ + i] : 0.f;
        __syncthreads();

        // thread owns tau = tau0..tau0+7 ; acc[k] = sum_j dEx[j-(tau0+k)] * w[j]
        const int tau0 = (tbeg - tsel) + tid * 8;
        const float4* dx4 = (const float4*)&dEx[C - tau0];   // (C - tau0) % 4 == 0
        const float4* w4 = (const float4*)w;
        const int Lp = (L + 7) & ~7;
        float acc[8] = {0.f, 0.f, 0.f, 0.f, 0.f, 0.f, 0.f, 0.f};
        float h[16];
        float4 p0 = dx4[-2], p1 = dx4[-1];
        h[0] = p0.x; h[1] = p0.y; h[2] = p0.z; h[3] = p0.w;
        h[4] = p1.x; h[5] = p1.y; h[6] = p1.z; h[7] = p1.w;
        for (int j = 0; j < Lp; j += 8) {
            float4 c0 = dx4[(j >> 2)];
            float4 c1 = dx4[(j >> 2) + 1];
            float4 q0 = w4[j >> 2];
            float4 q1 = w4[(j >> 2) + 1];
            h[8] = c0.x;  h[9] = c0.y;  h[10] = c0.z; h[11] = c0.w;
            h[12] = c1.x; h[13] = c1.y; h[14] = c1.z; h[15] = c1.w;
            float wv[8] = {q0.x, q0.y, q0.z, q0.w, q1.x, q1.y, q1.z, q1.w};
            #pragma unroll
            for (int u = 0; u < 8; ++u)
                #pragma unroll
                for (int k = 0; k < 8; ++k)
                    acc[k] = fmaf(h[8 + u - k], wv[u], acc[k]);
            #pragma unroll
            for (int m = 0; m < 8; ++m) h[m] = h[m + 8];
        }
        #pragma unroll
        for (int k = 0; k < 8; ++k) {
            int t = tbeg + tid * 8 + k;      // coalesced
            if (t < tend) fm[rowoff + t] -= inv_aB * acc[k];
        }
        __syncthreads();
    }

    // ---- phase C: rescan <=2 affected segments in place, then row max ----
    for (int s = s0; s <= s1; ++s) {
        const float4* rp = (const float4*)(fm + rowoff + s * SEG_);
        unsigned long long m = 0ull;
        #pragma unroll
        for (int r = 0; r < 2; ++r) {
            int i4 = tid + r * 128;
            float4 f = rp[i4];
            unsigned int base = (unsigned int)(aB * T_ + s * SEG_ + i4 * 4);
            m = umax64(m, (((unsigned long long)encf(f.x)) << 32) | (unsigned int)~(base + 0));
            m = umax64(m, (((unsigned long long)encf(f.y)) << 32) | (unsigned int)~(base + 1));
            m = umax64(m, (((unsigned long long)encf(f.z)) << 32) | (unsigned int)~(base + 2));
            m = umax64(m, (((unsigned long long)encf(f.w)) << 32) | (unsigned int)~(base + 3));
        }
        redU[tid] = m;
        __syncthreads();
        for (int t2 = 64; t2 > 0; t2 >>= 1) {
            if (tid < t2) redU[tid] = umax64(redU[tid], redU[tid + t2]);
            __syncthreads();
        }
        if (tid == 0) segrow[s] = redU[0];
        __syncthreads();
    }
    if (tid < NSEG_) redU[tid] = segrow[tid];
    __syncthreads();
    if (tid == 0) {
        unsigned long long m = redU[0];
        #pragma unroll
        for (int i = 1; i < NSEG_; ++i) m = umax64(m, redU[i]);
        rmNew[gb * NA_ + aB] = m;
    }
}

// ---------------- slow fallback (tiny ws): residual-space recompute ----------------
__global__ void s_init(const float* __restrict__ x, float* __restrict__ xr,
                       unsigned long long* __restrict__ cand) {
    int i = blockIdx.x * 256 + threadIdx.x;
    if (i < B_ * T_) xr[i] = x[i];
    if (i < B_) cand[i] = 0ull;
}
__global__ __launch_bounds__(256) void s_scan(const float* __restrict__ xr,
                                              const float* __restrict__ d,
                                              const float* __restrict__ inv,
                                              unsigned long long* __restrict__ cand) {
    __shared__ float dL[A_];
    __shared__ unsigned long long redU[256];
    const int aB = blockIdx.x, b = blockIdx.y, tid = threadIdx.x;
    const float iv = inv[aB];
    for (int i = tid; i < A_; i += 256) dL[i] = d[aB * A_ + i] * iv;
    __syncthreads();
    const float* xb = xr + b * T_;
    unsigned long long best = 0ull;
    for (int t = tid; t < T_; t += 256) {
        float acc = 0.f;
        int lim = min(A_, T_ - t);
        for (int i = 0; i < lim; ++i) acc = fmaf(dL[i], xb[t + i], acc);
        unsigned int flat = (unsigned int)(aB * T_ + t);
        unsigned long long c = (((unsigned long long)encf(acc)) << 32) | (unsigned int)~flat;
        best = umax64(best, c);
    }
    redU[tid] = best;
    __syncthreads();
    for (int s = 128; s > 0; s >>= 1) {
        if (tid < s) redU[tid] = umax64(redU[tid], redU[tid + s]);
        __syncthreads();
    }
    if (tid == 0) atomicMax(&cand[b], redU[0]);
}
__global__ void s_apply(float* __restrict__ xr, const float* __restrict__ d,
                        const float* __restrict__ inv,
                        unsigned long long* __restrict__ cand,
                        int* selA, int* selT, float* selV, int it) {
    const int b = blockIdx.x, tid = threadIdx.x;
    unsigned long long win = cand[b];
    unsigned int enc = (unsigned int)(win >> 32);
    unsigned int flat = ~(unsigned int)win;
    int a = (int)(flat >> 14), t = (int)(flat & (T_ - 1));
    float v = decf(enc);
    if (tid == 0) { selA[it * B_ + b] = a; selT[it * B_ + b] = t; selV[it * B_ + b] = v; }
    float vv = v * inv[a];
    int L = min(A_, (T_ - 1) - t);
    for (int o = tid; o < L; o += 256) xr[b * T_ + t + o] -= vv * d[a * A_ + o];
    if (tid == 0) cand[b] = 0ull;
}

// ---------------- reconstruct (residual, recon); sc = [selA selT selV inv] in ws ----------------
__global__ __launch_bounds__(256) void k_final(const float* __restrict__ x,
                                               const float* __restrict__ d,
                                               const float* __restrict__ sc,
                                               float* __restrict__ out) {
    const int gid = blockIdx.x * 256 + threadIdx.x;
    const int b = gid >> 14;
    const int t = gid & (T_ - 1);
    const int* selA = (const int*)sc;
    const int* selT = (const int*)(sc + 256);
    const float* selV = sc + 512;
    const float* inv = sc + 768;
    float r = x[gid];
    float rec = 0.f;
    for (int k = 0; k < NIT_; ++k) {          // sequential: reference fp order
        int a  = selA[k * B_ + b];
        int ts = selT[k * B_ + b];
        float vv = selV[k * B_ + b] * inv[a];
        int o = t - ts;
        int L = min(A_, (T_ - 1) - ts);
        if (o >= 0 && o < L) {
            float c = vv * d[a * A_ + o];
            r -= c;
            rec += c;
        }
    }
    out[gid] = r;
    out[B_ * T_ + gid] = rec;
}

extern "C" void kernel_launch(void* const* d_in, const int* in_sizes, int n_in,
                              void* d_out, int out_size, void* d_ws, size_t ws_size,
                              hipStream_t stream) {
    const float* x = (const float*)d_in[0];
    const float* d = (const float*)d_in[1];
    float* out = (float*)d_out;
    float* ws = (float*)d_ws;
    const size_t wsf = ws_size / sizeof(float);

    unsigned long long* seg = (unsigned long long*)(out + DO_SEG);
    unsigned long long* rmA = (unsigned long long*)(out + DO_RMA);
    unsigned long long* rmB = (unsigned long long*)(out + DO_RMB);
    int*   selA = (int*)(out + DO_SEL);
    int*   selT = selA + 256;
    float* selV = (float*)(selT + 256);
    float* inv  = out + DO_INV;

    int G = 0;
    for (int g = 8; g >= 1; g >>= 1)
        if ((size_t)g * NA_ * T_ <= wsf) { G = g; break; }
    if (G == 0 && wsf < DO_SCN) return;   // hopeless

    k_inv<<<dim3(NA_), dim3(64), 0, stream>>>(d, inv);

    if (G > 0) {
        float* fm = ws;
        const int nseg = G * NA_ * NSEG_;
        for (int bg0 = 0; bg0 < B_; bg0 += G) {
            k_init<<<dim3((nseg + 255) / 256), dim3(256), 0, stream>>>(seg, nseg);
            k_conv<<<dim3(T_ / 128, NA_ / 64, G), dim3(256), 0, stream>>>(x, d, inv, fm, seg, bg0);
            k_rowmax<<<dim3((G * NA_ + 255) / 256), dim3(256), 0, stream>>>(seg, rmA, G * NA_);
            for (int it = 0; it < NIT_; ++it) {
                unsigned long long* ro = (it & 1) ? rmB : rmA;
                unsigned long long* rn = (it & 1) ? rmA : rmB;
                k_iter<<<dim3(NA_, G), dim3(128), 0, stream>>>(fm, d, inv, seg, ro, rn,
                                                               selA, selT, selV, it, bg0);
            }
        }
    } else {
        float* xr = out + DO_SEG;                               // reuse d_out scratch
        unsigned long long* cand = (unsigned long long*)(out + 131072);
        s_init<<<dim3((B_ * T_ + 255) / 256), dim3(256), 0, stream>>>(x, xr, cand);
        for (int it = 0; it < NIT_; ++it) {
            s_scan<<<dim3(NA_, B_), dim3(256), 0, stream>>>(xr, d, inv, cand);
            s_apply<<<dim3(B_), dim3(256), 0, stream>>>(xr, d, inv, cand, selA, selT, selV, it);
        }
    }

    // park sel+inv in ws (fm is dead), then k_final overwrites all of d_out
    hipMemcpyAsync(ws, out + DO_SEL, DO_SCN * sizeof(float), hipMemcpyDeviceToDevice, stream);
    k_final<<<dim3(B_ * T_ / 256), dim3(256), 0, stream>>>(x, d, ws, out);
}

// Round 4
// 3706.366 us; speedup vs baseline: 1.7041x; 1.7041x over previous
//
#include <hip/hip_runtime.h>
#include <cstdint>

#define B_    8
#define T_    16384
#define NA_   512
#define A_    512
#define NIT_  32
#define NCH_  256          // 64-sample chunks per row
#define EPSV  1e-8f
#define WMAX  1664
#define XWPHYS 1882        // WMAX + WMAX/8 + pad

typedef unsigned long long u64;

// ws float-offset layout (9.5 MB total)
#define OFF_INV   0
#define OFF_SELA  512
#define OFF_SELT  768
#define OFF_SELV  1024
#define OFF_CM    1280        // u64[B_*NA_*NCH_] = 2,097,152 floats
#define OFF_RMA   2098432     // u64[4096]
#define OFF_RMB   2106624
#define OFF_XRA   2114816
#define OFF_XRB   2245888
#define MAIN_NEED 2376960
// compact fallback layout
#define OFF_SXR   2048
#define OFF_SCAND (2048 + 131072)
#define S_NEED    (OFF_SCAND + 16)

__device__ __forceinline__ unsigned int encf(float f) {
    unsigned int u = __float_as_uint(f);
    return (u & 0x80000000u) ? ~u : (u | 0x80000000u);
}
__device__ __forceinline__ float decf(unsigned int e) {
    unsigned int u = (e & 0x80000000u) ? (e & 0x7fffffffu) : ~e;
    return __uint_as_float(u);
}
__device__ __forceinline__ u64 umax64(u64 a, u64 b) { return a > b ? a : b; }
__device__ __forceinline__ u64 enc64(float v, unsigned int flat) {
    return (((u64)encf(v)) << 32) | (unsigned int)~flat;
}
__device__ __forceinline__ u64 shfl_xor_u64(u64 v, int mask) {
    unsigned int lo = (unsigned int)v, hi = (unsigned int)(v >> 32);
    lo = __shfl_xor(lo, mask, 64);
    hi = __shfl_xor(hi, mask, 64);
    return (((u64)hi) << 32) | lo;
}
__device__ __forceinline__ u64 shfl_down_u64(u64 v, int off) {
    unsigned int lo = (unsigned int)v, hi = (unsigned int)(v >> 32);
    lo = __shfl_down(lo, off, 64);
    hi = __shfl_down(hi, off, 64);
    return (((u64)hi) << 32) | lo;
}

// ---------------- inv[a] = 1/(||d_a||+eps) ----------------
__global__ __launch_bounds__(64) void k_inv(const float* __restrict__ d, float* __restrict__ inv) {
    const int a = blockIdx.x, lane = threadIdx.x;
    const float* row = d + a * A_;
    float s = 0.f;
    for (int i = lane; i < A_; i += 64) { float v = row[i]; s = fmaf(v, v, s); }
    #pragma unroll
    for (int o = 32; o > 0; o >>= 1) s += __shfl_down(s, o, 64);
    if (lane == 0) inv[a] = 1.0f / (sqrtf(s) + EPSV);
}

// ---------------- full conv -> chunk-max table only (no fm store) ----------------
__global__ __launch_bounds__(256) void k_conv(const float* __restrict__ x,
                                              const float* __restrict__ d,
                                              const float* __restrict__ inv,
                                              u64* __restrict__ cm) {
    __shared__ float As[32][68];
    __shared__ float Xs[160];
    const int tid = threadIdx.x;
    const int t0 = blockIdx.x * 128;
    const int a0 = blockIdx.y * 64;
    const int gb = blockIdx.z;
    const int tt = tid & 31;
    const int mb = tid >> 5;
    const float* xb = x + gb * T_;

    float acc[8][4];
    #pragma unroll
    for (int p = 0; p < 8; ++p)
        #pragma unroll
        for (int q = 0; q < 4; ++q) acc[p][q] = 0.f;

    for (int k0 = 0; k0 < A_; k0 += 32) {
        #pragma unroll
        for (int mm = 0; mm < 8; ++mm) {
            int m = mb * 8 + mm;
            As[tt][m] = d[(a0 + m) * A_ + k0 + tt];
        }
        if (tid < 160) {
            int g = t0 + k0 + tid;
            Xs[tid] = (g < T_) ? xb[g] : 0.f;
        }
        __syncthreads();
        #pragma unroll 8
        for (int k = 0; k < 32; ++k) {
            float4 aA = *(const float4*)&As[k][mb * 8];
            float4 aB = *(const float4*)&As[k][mb * 8 + 4];
            float am[8] = {aA.x, aA.y, aA.z, aA.w, aB.x, aB.y, aB.z, aB.w};
            float xm[4] = {Xs[k + tt], Xs[k + tt + 32], Xs[k + tt + 64], Xs[k + tt + 96]};
            #pragma unroll
            for (int p = 0; p < 8; ++p)
                #pragma unroll
                for (int q = 0; q < 4; ++q)
                    acc[p][q] = fmaf(am[p], xm[q], acc[p][q]);
        }
        __syncthreads();
    }

    const int ch0 = t0 >> 6;
    #pragma unroll
    for (int p = 0; p < 8; ++p) {
        const int a = a0 + mb * 8 + p;
        const float iv = inv[a];
        unsigned int f0 = (unsigned int)(a * T_ + t0 + tt);
        u64 c0 = umax64(enc64(acc[p][0] * iv, f0), enc64(acc[p][1] * iv, f0 + 32));
        u64 c1 = umax64(enc64(acc[p][2] * iv, f0 + 64), enc64(acc[p][3] * iv, f0 + 96));
        #pragma unroll
        for (int o = 1; o < 32; o <<= 1) {
            c0 = umax64(c0, shfl_xor_u64(c0, o));
            c1 = umax64(c1, shfl_xor_u64(c1, o));
        }
        if (tt == 0) {
            size_t row = (size_t)(gb * NA_ + a) * NCH_;
            cm[row + ch0] = c0;
            cm[row + ch0 + 1] = c1;
        }
    }
}

// ---------------- initial rm from cm (4 rows per block, wave per row) ----------------
__global__ __launch_bounds__(256) void k_tables(const u64* __restrict__ cm, u64* __restrict__ rm) {
    const int row = blockIdx.x * 4 + (threadIdx.x >> 6);
    const int lane = threadIdx.x & 63;
    const u64* p = cm + (size_t)row * NCH_;
    u64 m = 0ull;
    #pragma unroll
    for (int k = 0; k < 4; ++k) m = umax64(m, p[lane + 64 * k]);
    #pragma unroll
    for (int o = 32; o > 0; o >>= 1) m = umax64(m, shfl_down_u64(m, o));
    if (lane == 0) rm[row] = m;
}

// ---------------- one full iteration: select + patch + window recompute + tables ----------------
__global__ __launch_bounds__(256) void k_iter(const float* __restrict__ xrPrev,
                                              float* __restrict__ xrNext,
                                              const float* __restrict__ d,
                                              const float* __restrict__ inv,
                                              u64* __restrict__ cm,
                                              const u64* __restrict__ rmPrev,
                                              u64* __restrict__ rmNext,
                                              int* __restrict__ selA,
                                              int* __restrict__ selT,
                                              float* __restrict__ selV,
                                              int it) {
    __shared__ u64 redU[256];
    __shared__ float xW[XWPHYS];
    __shared__ float dL[A_];
    const int aB = blockIdx.x, gb = blockIdx.y, tid = threadIdx.x;

    // phase A: argmax from rm (all blocks identical)
    const u64* rp = rmPrev + gb * NA_;
    redU[tid] = umax64(rp[tid], rp[tid + 256]);
    __syncthreads();
    for (int s = 128; s > 0; s >>= 1) {
        if (tid < s) redU[tid] = umax64(redU[tid], redU[tid + s]);
        __syncthreads();
    }
    const u64 win = redU[0];
    __syncthreads();
    const unsigned int enc = (unsigned int)(win >> 32);
    const unsigned int flat = ~(unsigned int)win;
    const int asel = (int)(flat >> 14);
    const int tsel = (int)(flat & (T_ - 1));
    const float v = decf(enc);
    if (aB == 0 && tid == 0) {
        selA[it * B_ + gb] = asel;
        selT[it * B_ + gb] = tsel;
        selV[it * B_ + gb] = v;
    }
    const int L = min(A_, (T_ - 1) - tsel);   // reference truncation quirk
    const float vv = v * inv[asel];

    // persist xr for next iter: block aB owns t in [aB*32, aB*32+32), patch fused
    if (tid < 32) {
        int t = aB * 32 + tid;
        float xv = xrPrev[gb * T_ + t];
        int o = t - tsel;
        if (o >= 0 && o < L) xv = fmaf(-vv, d[asel * A_ + o], xv);
        xrNext[gb * T_ + t] = xv;
    }

    if (L > 0) {
        const int tbeg = max(0, tsel - (A_ - 1));
        const int tend = tsel + L;              // exclusive, <= 16383
        const int ab = tbeg & ~63;              // chunk-aligned window
        const int ae = (tend + 63) & ~63;       // <= T_
        const int W = ae - ab;                  // <= 1152, multiple of 64
        const int nst = W + A_;                 // <= 1664

        // stage patched residual window (swizzled: idx + idx/8 kills stride-8 conflicts)
        for (int i = tid; i < nst; i += 256) {
            int t = ab + i;
            float xv = (t < T_) ? xrPrev[gb * T_ + t] : 0.f;
            int o = t - tsel;
            if (o >= 0 && o < L) xv = fmaf(-vv, d[asel * A_ + o], xv);
            xW[i + (i >> 3)] = xv;
        }
        for (int i = tid; i < A_; i += 256) dL[i] = d[aB * A_ + i];
        __syncthreads();

        const int base = tid * 8;               // 8 consecutive t per thread
        if (base < W) {
            const float iv = inv[aB];
            float acc[8] = {0.f, 0.f, 0.f, 0.f, 0.f, 0.f, 0.f, 0.f};
            float h[16];
            #define XWL(ix) xW[(ix) + ((ix) >> 3)]
            #pragma unroll
            for (int m = 0; m < 8; ++m) h[m] = XWL(base + m);
            for (int i0 = 0; i0 < A_; i0 += 8) {
                #pragma unroll
                for (int m = 0; m < 8; ++m) h[8 + m] = XWL(base + i0 + 8 + m);
                #pragma unroll
                for (int u = 0; u < 8; ++u) {
                    float dv = dL[i0 + u];       // lane-uniform: LDS broadcast
                    #pragma unroll
                    for (int k = 0; k < 8; ++k)
                        acc[k] = fmaf(h[u + k], dv, acc[k]);
                }
                #pragma unroll
                for (int m = 0; m < 8; ++m) h[m] = h[m + 8];
            }
            // chunk max: 8 lanes (64 t) per chunk, then write cm
            u64 c = 0ull;
            #pragma unroll
            for (int k = 0; k < 8; ++k) {
                unsigned int fl = (unsigned int)(aB * T_ + ab + base + k);
                c = umax64(c, enc64(acc[k] * iv, fl));
            }
            c = umax64(c, shfl_xor_u64(c, 1));
            c = umax64(c, shfl_xor_u64(c, 2));
            c = umax64(c, shfl_xor_u64(c, 4));
            if ((tid & 7) == 0)
                cm[(size_t)(gb * NA_ + aB) * NCH_ + (ab >> 6) + (tid >> 3)] = c;
        }
        __syncthreads();   // cm writes visible block-wide before rescan
    }

    // phase C: new row max from the 256 cm entries
    const u64* crow = cm + (size_t)(gb * NA_ + aB) * NCH_;
    redU[tid] = crow[tid];
    __syncthreads();
    for (int s = 128; s > 0; s >>= 1) {
        if (tid < s) redU[tid] = umax64(redU[tid], redU[tid + s]);
        __syncthreads();
    }
    if (tid == 0) rmNext[gb * NA_ + aB] = redU[0];
}

// ---------------- slow fallback (tiny ws): residual-space recompute ----------------
__global__ void s_init(const float* __restrict__ x, float* __restrict__ xr,
                       u64* __restrict__ cand) {
    int i = blockIdx.x * 256 + threadIdx.x;
    if (i < B_ * T_) xr[i] = x[i];
    if (i < B_) cand[i] = 0ull;
}
__global__ __launch_bounds__(256) void s_scan(const float* __restrict__ xr,
                                              const float* __restrict__ d,
                                              const float* __restrict__ inv,
                                              u64* __restrict__ cand) {
    __shared__ float dLs[A_];
    __shared__ u64 redU[256];
    const int aB = blockIdx.x, b = blockIdx.y, tid = threadIdx.x;
    const float iv = inv[aB];
    for (int i = tid; i < A_; i += 256) dLs[i] = d[aB * A_ + i] * iv;
    __syncthreads();
    const float* xb = xr + b * T_;
    u64 best = 0ull;
    for (int t = tid; t < T_; t += 256) {
        float acc = 0.f;
        int lim = min(A_, T_ - t);
        for (int i = 0; i < lim; ++i) acc = fmaf(dLs[i], xb[t + i], acc);
        best = umax64(best, enc64(acc, (unsigned int)(aB * T_ + t)));
    }
    redU[tid] = best;
    __syncthreads();
    for (int s = 128; s > 0; s >>= 1) {
        if (tid < s) redU[tid] = umax64(redU[tid], redU[tid + s]);
        __syncthreads();
    }
    if (tid == 0) atomicMax(&cand[b], redU[0]);
}
__global__ void s_apply(float* __restrict__ xr, const float* __restrict__ d,
                        const float* __restrict__ inv, u64* __restrict__ cand,
                        int* selA, int* selT, float* selV, int it) {
    const int b = blockIdx.x, tid = threadIdx.x;
    u64 win = cand[b];
    unsigned int enc = (unsigned int)(win >> 32);
    unsigned int flat = ~(unsigned int)win;
    int a = (int)(flat >> 14), t = (int)(flat & (T_ - 1));
    float v = decf(enc);
    if (tid == 0) { selA[it * B_ + b] = a; selT[it * B_ + b] = t; selV[it * B_ + b] = v; }
    float vvl = v * inv[a];
    int L = min(A_, (T_ - 1) - t);
    for (int o = tid; o < L; o += 256) xr[b * T_ + t + o] -= vvl * d[a * A_ + o];
    if (tid == 0) cand[b] = 0ull;
}

// ---------------- reconstruct (residual, recon) from selections ----------------
__global__ __launch_bounds__(256) void k_final(const float* __restrict__ x,
                                               const float* __restrict__ d,
                                               const int* __restrict__ selA,
                                               const int* __restrict__ selT,
                                               const float* __restrict__ selV,
                                               const float* __restrict__ inv,
                                               float* __restrict__ out) {
    const int gid = blockIdx.x * 256 + threadIdx.x;
    const int b = gid >> 14;
    const int t = gid & (T_ - 1);
    float r = x[gid];
    float rec = 0.f;
    for (int k = 0; k < NIT_; ++k) {           // sequential: reference fp order
        int a  = selA[k * B_ + b];
        int ts = selT[k * B_ + b];
        float vvl = selV[k * B_ + b] * inv[a];
        int o = t - ts;
        int L = min(A_, (T_ - 1) - ts);
        if (o >= 0 && o < L) {
            float c = vvl * d[a * A_ + o];
            r -= c;
            rec += c;
        }
    }
    out[gid] = r;
    out[B_ * T_ + gid] = rec;
}

extern "C" void kernel_launch(void* const* d_in, const int* in_sizes, int n_in,
                              void* d_out, int out_size, void* d_ws, size_t ws_size,
                              hipStream_t stream) {
    const float* x = (const float*)d_in[0];
    const float* d = (const float*)d_in[1];
    float* out = (float*)d_out;
    float* ws = (float*)d_ws;
    const size_t wsf = ws_size / sizeof(float);

    float* inv  = ws + OFF_INV;
    int*   selA = (int*)(ws + OFF_SELA);
    int*   selT = (int*)(ws + OFF_SELT);
    float* selV = ws + OFF_SELV;

    if (wsf < (size_t)S_NEED) return;   // hopeless

    k_inv<<<dim3(NA_), dim3(64), 0, stream>>>(d, inv);

    if (wsf >= (size_t)MAIN_NEED) {
        u64* cm  = (u64*)(ws + OFF_CM);
        u64* rmA = (u64*)(ws + OFF_RMA);
        u64* rmB = (u64*)(ws + OFF_RMB);
        float* xrA = ws + OFF_XRA;
        float* xrB = ws + OFF_XRB;
        hipMemcpyAsync(xrA, x, (size_t)B_ * T_ * sizeof(float),
                       hipMemcpyDeviceToDevice, stream);
        k_conv<<<dim3(T_ / 128, NA_ / 64, B_), dim3(256), 0, stream>>>(x, d, inv, cm);
        k_tables<<<dim3(B_ * NA_ / 4), dim3(256), 0, stream>>>(cm, rmA);
        for (int it = 0; it < NIT_; ++it) {
            const float* xp = (it & 1) ? xrB : xrA;
            float*       xn = (it & 1) ? xrA : xrB;
            const u64*   ro = (it & 1) ? rmB : rmA;
            u64*         rn = (it & 1) ? rmA : rmB;
            k_iter<<<dim3(NA_, B_), dim3(256), 0, stream>>>(xp, xn, d, inv, cm, ro, rn,
                                                            selA, selT, selV, it);
        }
    } else {
        float* xr = ws + OFF_SXR;
        u64* cand = (u64*)(ws + OFF_SCAND);
        s_init<<<dim3((B_ * T_ + 255) / 256), dim3(256), 0, stream>>>(x, xr, cand);
        for (int it = 0; it < NIT_; ++it) {
            s_scan<<<dim3(NA_, B_), dim3(256), 0, stream>>>(xr, d, inv, cand);
            s_apply<<<dim3(B_), dim3(256), 0, stream>>>(xr, d, inv, cand, selA, selT, selV, it);
        }
    }

    k_final<<<dim3(B_ * T_ / 256), dim3(256), 0, stream>>>(x, d, selA, selT, selV, inv, out);
}

// Round 5
// 3655.882 us; speedup vs baseline: 1.7276x; 1.0138x over previous
//
#include <hip/hip_runtime.h>
#include <cstdint>

#define B_    8
#define T_    16384
#define NA_   512
#define A_    512
#define NIT_  32
#define NCH_  256          // 64-sample chunks per row
#define EPSV  1e-8f
#define WMAX  1664
#define XWPHYS 1882        // WMAX + WMAX/8 + pad

typedef unsigned long long u64;

// ws float-offset layout (9.5 MB total)
#define OFF_INV   0
#define OFF_SELA  512
#define OFF_SELT  768
#define OFF_SELV  1024
#define OFF_CM    1280        // u64[B_*NA_*NCH_] = 2,097,152 floats
#define OFF_RMA   2098432     // u64[4096]
#define OFF_RMB   2106624
#define OFF_XRA   2114816
#define OFF_XRB   2245888
#define MAIN_NEED 2376960
// compact fallback layout
#define OFF_SXR   2048
#define OFF_SCAND (2048 + 131072)
#define S_NEED    (OFF_SCAND + 16)

__device__ __forceinline__ unsigned int encf(float f) {
    unsigned int u = __float_as_uint(f);
    return (u & 0x80000000u) ? ~u : (u | 0x80000000u);
}
__device__ __forceinline__ float decf(unsigned int e) {
    unsigned int u = (e & 0x80000000u) ? (e & 0x7fffffffu) : ~e;
    return __uint_as_float(u);
}
__device__ __forceinline__ u64 umax64(u64 a, u64 b) { return a > b ? a : b; }
__device__ __forceinline__ u64 enc64(float v, unsigned int flat) {
    return (((u64)encf(v)) << 32) | (unsigned int)~flat;
}
__device__ __forceinline__ u64 shfl_xor_u64(u64 v, int mask) {
    unsigned int lo = (unsigned int)v, hi = (unsigned int)(v >> 32);
    lo = __shfl_xor(lo, mask, 64);
    hi = __shfl_xor(hi, mask, 64);
    return (((u64)hi) << 32) | lo;
}
__device__ __forceinline__ u64 shfl_down_u64(u64 v, int off) {
    unsigned int lo = (unsigned int)v, hi = (unsigned int)(v >> 32);
    lo = __shfl_down(lo, off, 64);
    hi = __shfl_down(hi, off, 64);
    return (((u64)hi) << 32) | lo;
}

// ---------------- inv[a] = 1/(||d_a||+eps) ----------------
__global__ __launch_bounds__(64) void k_inv(const float* __restrict__ d, float* __restrict__ inv) {
    const int a = blockIdx.x, lane = threadIdx.x;
    const float* row = d + a * A_;
    float s = 0.f;
    for (int i = lane; i < A_; i += 64) { float v = row[i]; s = fmaf(v, v, s); }
    #pragma unroll
    for (int o = 32; o > 0; o >>= 1) s += __shfl_down(s, o, 64);
    if (lane == 0) inv[a] = 1.0f / (sqrtf(s) + EPSV);
}

// ---------------- full conv -> chunk-max table only (no fm store) ----------------
// register-prefetch software pipeline: global loads for k0+32 issue before the
// FMA loop on k0, hiding L2/HBM latency under 2048 FMA cycles.
__global__ __launch_bounds__(256) void k_conv(const float* __restrict__ x,
                                              const float* __restrict__ d,
                                              const float* __restrict__ inv,
                                              u64* __restrict__ cm) {
    __shared__ float As[32][68];
    __shared__ float Xs[160];
    const int tid = threadIdx.x;
    const int t0 = blockIdx.x * 128;
    const int a0 = blockIdx.y * 64;
    const int gb = blockIdx.z;
    const int tt = tid & 31;
    const int mb = tid >> 5;
    const float* xb = x + gb * T_;

    float acc[8][4];
    #pragma unroll
    for (int p = 0; p < 8; ++p)
        #pragma unroll
        for (int q = 0; q < 4; ++q) acc[p][q] = 0.f;

    float rA[8];
    float rX = 0.f;
    #pragma unroll
    for (int mm = 0; mm < 8; ++mm)
        rA[mm] = d[(a0 + mb * 8 + mm) * A_ + tt];
    if (tid < 160) {
        int g = t0 + tid;
        rX = (g < T_) ? xb[g] : 0.f;
    }

    for (int k0 = 0; k0 < A_; k0 += 32) {
        if (k0) __syncthreads();             // prev FMA done before overwrite
        #pragma unroll
        for (int mm = 0; mm < 8; ++mm) As[tt][mb * 8 + mm] = rA[mm];
        if (tid < 160) Xs[tid] = rX;
        if (k0 + 32 < A_) {                  // prefetch next chunk
            #pragma unroll
            for (int mm = 0; mm < 8; ++mm)
                rA[mm] = d[(a0 + mb * 8 + mm) * A_ + k0 + 32 + tt];
            if (tid < 160) {
                int g = t0 + k0 + 32 + tid;
                rX = (g < T_) ? xb[g] : 0.f;
            }
        }
        __syncthreads();
        #pragma unroll 8
        for (int k = 0; k < 32; ++k) {
            float4 aA = *(const float4*)&As[k][mb * 8];
            float4 aB = *(const float4*)&As[k][mb * 8 + 4];
            float am[8] = {aA.x, aA.y, aA.z, aA.w, aB.x, aB.y, aB.z, aB.w};
            float xm[4] = {Xs[k + tt], Xs[k + tt + 32], Xs[k + tt + 64], Xs[k + tt + 96]};
            #pragma unroll
            for (int p = 0; p < 8; ++p)
                #pragma unroll
                for (int q = 0; q < 4; ++q)
                    acc[p][q] = fmaf(am[p], xm[q], acc[p][q]);
        }
    }

    const int ch0 = t0 >> 6;
    #pragma unroll
    for (int p = 0; p < 8; ++p) {
        const int a = a0 + mb * 8 + p;
        const float iv = inv[a];
        unsigned int f0 = (unsigned int)(a * T_ + t0 + tt);
        u64 c0 = umax64(enc64(acc[p][0] * iv, f0), enc64(acc[p][1] * iv, f0 + 32));
        u64 c1 = umax64(enc64(acc[p][2] * iv, f0 + 64), enc64(acc[p][3] * iv, f0 + 96));
        #pragma unroll
        for (int o = 1; o < 32; o <<= 1) {
            c0 = umax64(c0, shfl_xor_u64(c0, o));
            c1 = umax64(c1, shfl_xor_u64(c1, o));
        }
        if (tt == 0) {
            size_t row = (size_t)(gb * NA_ + a) * NCH_;
            cm[row + ch0] = c0;
            cm[row + ch0 + 1] = c1;
        }
    }
}

// ---------------- initial rm from cm (4 rows per block, wave per row) ----------------
__global__ __launch_bounds__(256) void k_tables(const u64* __restrict__ cm, u64* __restrict__ rm) {
    const int row = blockIdx.x * 4 + (threadIdx.x >> 6);
    const int lane = threadIdx.x & 63;
    const u64* p = cm + (size_t)row * NCH_;
    u64 m = 0ull;
    #pragma unroll
    for (int k = 0; k < 4; ++k) m = umax64(m, p[lane + 64 * k]);
    #pragma unroll
    for (int o = 32; o > 0; o >>= 1) m = umax64(m, shfl_down_u64(m, o));
    if (lane == 0) rm[row] = m;
}

// ---------------- one full iteration: select + patch + window recompute + tables ----------------
__global__ __launch_bounds__(256) void k_iter(const float* __restrict__ xrPrev,
                                              float* __restrict__ xrNext,
                                              const float* __restrict__ d,
                                              const float* __restrict__ inv,
                                              u64* __restrict__ cm,
                                              const u64* __restrict__ rmPrev,
                                              u64* __restrict__ rmNext,
                                              int* __restrict__ selA,
                                              int* __restrict__ selT,
                                              float* __restrict__ selV,
                                              int it) {
    __shared__ u64 redU[256];
    __shared__ float xW[XWPHYS];
    __shared__ float dL[A_];
    const int aB = blockIdx.x, gb = blockIdx.y, tid = threadIdx.x;

    // phase A: argmax from rm (all blocks identical)
    const u64* rp = rmPrev + gb * NA_;
    redU[tid] = umax64(rp[tid], rp[tid + 256]);
    __syncthreads();
    for (int s = 128; s > 0; s >>= 1) {
        if (tid < s) redU[tid] = umax64(redU[tid], redU[tid + s]);
        __syncthreads();
    }
    const u64 win = redU[0];
    __syncthreads();
    const unsigned int enc = (unsigned int)(win >> 32);
    const unsigned int flat = ~(unsigned int)win;
    const int asel = (int)(flat >> 14);
    const int tsel = (int)(flat & (T_ - 1));
    const float v = decf(enc);
    if (aB == 0 && tid == 0) {
        selA[it * B_ + gb] = asel;
        selT[it * B_ + gb] = tsel;
        selV[it * B_ + gb] = v;
    }
    const int L = min(A_, (T_ - 1) - tsel);   // reference truncation quirk
    const float vv = v * inv[asel];

    // persist xr for next iter: block aB owns t in [aB*32, aB*32+32), patch fused
    if (tid < 32) {
        int t = aB * 32 + tid;
        float xv = xrPrev[gb * T_ + t];
        int o = t - tsel;
        if (o >= 0 && o < L) xv = fmaf(-vv, d[asel * A_ + o], xv);
        xrNext[gb * T_ + t] = xv;
    }

    if (L > 0) {
        const int tbeg = max(0, tsel - (A_ - 1));
        const int tend = tsel + L;              // exclusive, <= 16383
        const int ab = tbeg & ~63;              // chunk-aligned window
        const int ae = (tend + 63) & ~63;       // <= T_
        const int W = ae - ab;                  // <= 1152, multiple of 64
        const int nst = W + A_;                 // <= 1664

        // stage patched residual window (swizzled: phys = idx + idx/8)
        for (int i = tid; i < nst; i += 256) {
            int t = ab + i;
            float xv = (t < T_) ? xrPrev[gb * T_ + t] : 0.f;
            int o = t - tsel;
            if (o >= 0 && o < L) xv = fmaf(-vv, d[asel * A_ + o], xv);
            xW[i + (i >> 3)] = xv;
        }
        for (int i = tid; i < A_; i += 256) dL[i] = d[aB * A_ + i];
        __syncthreads();

        const int base = tid * 8;               // 8 consecutive t per thread
        if (base < W) {
            const float iv = inv[aB];
            float acc[8] = {0.f, 0.f, 0.f, 0.f, 0.f, 0.f, 0.f, 0.f};
            float h[16];
            // phys(8s+m) = 9s+m: the swizzled layout is pointer-walkable.
            // one v_add per 8-j chunk; ds_reads use immediate offsets.
            const float* px = &xW[9 * tid];
            const float* pd = dL;
            #pragma unroll
            for (int m = 0; m < 8; ++m) h[m] = px[m];
            px += 9;
            #pragma unroll 2
            for (int i0 = 0; i0 < A_; i0 += 8) {
                #pragma unroll
                for (int m = 0; m < 8; ++m) h[8 + m] = px[m];
                px += 9;
                #pragma unroll
                for (int u = 0; u < 8; ++u) {
                    float dv = pd[u];            // lane-uniform: LDS broadcast
                    #pragma unroll
                    for (int k = 0; k < 8; ++k)
                        acc[k] = fmaf(h[u + k], dv, acc[k]);
                }
                pd += 8;
                #pragma unroll
                for (int m = 0; m < 8; ++m) h[m] = h[m + 8];
            }
            // chunk max: 8 lanes (64 t) per chunk, then write cm
            u64 c = 0ull;
            #pragma unroll
            for (int k = 0; k < 8; ++k) {
                unsigned int fl = (unsigned int)(aB * T_ + ab + base + k);
                c = umax64(c, enc64(acc[k] * iv, fl));
            }
            c = umax64(c, shfl_xor_u64(c, 1));
            c = umax64(c, shfl_xor_u64(c, 2));
            c = umax64(c, shfl_xor_u64(c, 4));
            if ((tid & 7) == 0)
                cm[(size_t)(gb * NA_ + aB) * NCH_ + (ab >> 6) + (tid >> 3)] = c;
        }
        __syncthreads();   // cm writes visible block-wide before rescan
    }

    // phase C: new row max from the 256 cm entries
    const u64* crow = cm + (size_t)(gb * NA_ + aB) * NCH_;
    redU[tid] = crow[tid];
    __syncthreads();
    for (int s = 128; s > 0; s >>= 1) {
        if (tid < s) redU[tid] = umax64(redU[tid], redU[tid + s]);
        __syncthreads();
    }
    if (tid == 0) rmNext[gb * NA_ + aB] = redU[0];
}

// ---------------- slow fallback (tiny ws): residual-space recompute ----------------
__global__ void s_init(const float* __restrict__ x, float* __restrict__ xr,
                       u64* __restrict__ cand) {
    int i = blockIdx.x * 256 + threadIdx.x;
    if (i < B_ * T_) xr[i] = x[i];
    if (i < B_) cand[i] = 0ull;
}
__global__ __launch_bounds__(256) void s_scan(const float* __restrict__ xr,
                                              const float* __restrict__ d,
                                              const float* __restrict__ inv,
                                              u64* __restrict__ cand) {
    __shared__ float dLs[A_];
    __shared__ u64 redU[256];
    const int aB = blockIdx.x, b = blockIdx.y, tid = threadIdx.x;
    const float iv = inv[aB];
    for (int i = tid; i < A_; i += 256) dLs[i] = d[aB * A_ + i] * iv;
    __syncthreads();
    const float* xb = xr + b * T_;
    u64 best = 0ull;
    for (int t = tid; t < T_; t += 256) {
        float acc = 0.f;
        int lim = min(A_, T_ - t);
        for (int i = 0; i < lim; ++i) acc = fmaf(dLs[i], xb[t + i], acc);
        best = umax64(best, enc64(acc, (unsigned int)(aB * T_ + t)));
    }
    redU[tid] = best;
    __syncthreads();
    for (int s = 128; s > 0; s >>= 1) {
        if (tid < s) redU[tid] = umax64(redU[tid], redU[tid + s]);
        __syncthreads();
    }
    if (tid == 0) atomicMax(&cand[b], redU[0]);
}
__global__ void s_apply(float* __restrict__ xr, const float* __restrict__ d,
                        const float* __restrict__ inv, u64* __restrict__ cand,
                        int* selA, int* selT, float* selV, int it) {
    const int b = blockIdx.x, tid = threadIdx.x;
    u64 win = cand[b];
    unsigned int enc = (unsigned int)(win >> 32);
    unsigned int flat = ~(unsigned int)win;
    int a = (int)(flat >> 14), t = (int)(flat & (T_ - 1));
    float v = decf(enc);
    if (tid == 0) { selA[it * B_ + b] = a; selT[it * B_ + b] = t; selV[it * B_ + b] = v; }
    float vvl = v * inv[a];
    int L = min(A_, (T_ - 1) - t);
    for (int o = tid; o < L; o += 256) xr[b * T_ + t + o] -= vvl * d[a * A_ + o];
    if (tid == 0) cand[b] = 0ull;
}

// ---------------- reconstruct (residual, recon) from selections ----------------
__global__ __launch_bounds__(256) void k_final(const float* __restrict__ x,
                                               const float* __restrict__ d,
                                               const int* __restrict__ selA,
                                               const int* __restrict__ selT,
                                               const float* __restrict__ selV,
                                               const float* __restrict__ inv,
                                               float* __restrict__ out) {
    const int gid = blockIdx.x * 256 + threadIdx.x;
    const int b = gid >> 14;
    const int t = gid & (T_ - 1);
    float r = x[gid];
    float rec = 0.f;
    for (int k = 0; k < NIT_; ++k) {           // sequential: reference fp order
        int a  = selA[k * B_ + b];
        int ts = selT[k * B_ + b];
        float vvl = selV[k * B_ + b] * inv[a];
        int o = t - ts;
        int L = min(A_, (T_ - 1) - ts);
        if (o >= 0 && o < L) {
            float c = vvl * d[a * A_ + o];
            r -= c;
            rec += c;
        }
    }
    out[gid] = r;
    out[B_ * T_ + gid] = rec;
}

extern "C" void kernel_launch(void* const* d_in, const int* in_sizes, int n_in,
                              void* d_out, int out_size, void* d_ws, size_t ws_size,
                              hipStream_t stream) {
    const float* x = (const float*)d_in[0];
    const float* d = (const float*)d_in[1];
    float* out = (float*)d_out;
    float* ws = (float*)d_ws;
    const size_t wsf = ws_size / sizeof(float);

    float* inv  = ws + OFF_INV;
    int*   selA = (int*)(ws + OFF_SELA);
    int*   selT = (int*)(ws + OFF_SELT);
    float* selV = ws + OFF_SELV;

    if (wsf < (size_t)S_NEED) return;   // hopeless

    k_inv<<<dim3(NA_), dim3(64), 0, stream>>>(d, inv);

    if (wsf >= (size_t)MAIN_NEED) {
        u64* cm  = (u64*)(ws + OFF_CM);
        u64* rmA = (u64*)(ws + OFF_RMA);
        u64* rmB = (u64*)(ws + OFF_RMB);
        float* xrA = ws + OFF_XRA;
        float* xrB = ws + OFF_XRB;
        hipMemcpyAsync(xrA, x, (size_t)B_ * T_ * sizeof(float),
                       hipMemcpyDeviceToDevice, stream);
        k_conv<<<dim3(T_ / 128, NA_ / 64, B_), dim3(256), 0, stream>>>(x, d, inv, cm);
        k_tables<<<dim3(B_ * NA_ / 4), dim3(256), 0, stream>>>(cm, rmA);
        for (int it = 0; it < NIT_; ++it) {
            const float* xp = (it & 1) ? xrB : xrA;
            float*       xn = (it & 1) ? xrA : xrB;
            const u64*   ro = (it & 1) ? rmB : rmA;
            u64*         rn = (it & 1) ? rmA : rmB;
            k_iter<<<dim3(NA_, B_), dim3(256), 0, stream>>>(xp, xn, d, inv, cm, ro, rn,
                                                            selA, selT, selV, it);
        }
    } else {
        float* xr = ws + OFF_SXR;
        u64* cand = (u64*)(ws + OFF_SCAND);
        s_init<<<dim3((B_ * T_ + 255) / 256), dim3(256), 0, stream>>>(x, xr, cand);
        for (int it = 0; it < NIT_; ++it) {
            s_scan<<<dim3(NA_, B_), dim3(256), 0, stream>>>(xr, d, inv, cand);
            s_apply<<<dim3(B_), dim3(256), 0, stream>>>(xr, d, inv, cand, selA, selT, selV, it);
        }
    }

    k_final<<<dim3(B_ * T_ / 256), dim3(256), 0, stream>>>(x, d, selA, selT, selV, inv, out);
}